// Round 2
// baseline (483.680 us; speedup 1.0000x reference)
//
#include <hip/hip_runtime.h>
#include <math.h>
#include <stdint.h>

constexpr int LL = 16384;
constexpr int HH = 8;
constexpr int DD = 16;
constexpr int NROW = 65536;          // N*L
constexpr int NPAIR = NROW * HH;     // 524288 (row,head) pairs
constexpr float EPS = 1e-6f;
constexpr float LN_EPS = 1e-5f;

// ws float offsets (stats region, zeroed each call)
constexpr int OFF_QSUM = 0;      // [4][8][16]
constexpr int OFF_KSUM = 512;
constexpr int OFF_QN   = 1024;
constexpr int OFF_KN   = 1536;
constexpr int OFF_SSUM = 2048;   // [4][8]
constexpr int OFF_KV   = 2112;   // [4][8][256]
constexpr int OFF_STATS_END = 10304;
// bf16 sigmoid mirrors after the stats region
constexpr size_t MIR_Q_BYTE = (size_t)OFF_STATS_END * 4;
constexpr size_t MIR_ELEMS  = (size_t)NPAIR * 16;
constexpr size_t MIR_K_BYTE = MIR_Q_BYTE + MIR_ELEMS * 2;
constexpr size_t WS_NEED    = MIR_K_BYTE + MIR_ELEMS * 2;

__device__ __forceinline__ float sigm(float x) { return __fdividef(1.f, 1.f + __expf(-x)); }
__device__ __forceinline__ unsigned short f2bf(float f) {
  uint32_t x = __float_as_uint(f);
  return (unsigned short)((x + 0x7FFFu + ((x >> 16) & 1u)) >> 16);
}
__device__ __forceinline__ float bf2f(unsigned short u) {
  return __uint_as_float(((uint32_t)u) << 16);
}

// load 16 sigmoid-activated values for pair p (row*8+h)
template <bool MIR>
__device__ __forceinline__ void load_sig(const unsigned short* mir, const float* fp, int p, float* r) {
  if (MIR) {
    const uint4* p4 = reinterpret_cast<const uint4*>(mir + (size_t)p * 16);
    uint4 a = p4[0], b = p4[1];
    uint32_t w[8] = {a.x, a.y, a.z, a.w, b.x, b.y, b.z, b.w};
#pragma unroll
    for (int j = 0; j < 8; ++j) {
      r[2 * j]     = bf2f((unsigned short)(w[j] & 0xFFFFu));
      r[2 * j + 1] = bf2f((unsigned short)(w[j] >> 16));
    }
  } else {
    const float4* p4 = reinterpret_cast<const float4*>(fp + (size_t)p * 16);
#pragma unroll
    for (int j = 0; j < 4; ++j) {
      float4 a = p4[j];
      r[4 * j] = sigm(a.x); r[4 * j + 1] = sigm(a.y);
      r[4 * j + 2] = sigm(a.z); r[4 * j + 3] = sigm(a.w);
    }
  }
}
__device__ __forceinline__ void load_raw16(const float* fp, int p, float* r) {
  const float4* p4 = reinterpret_cast<const float4*>(fp + (size_t)p * 16);
#pragma unroll
  for (int j = 0; j < 4; ++j) {
    float4 a = p4[j];
    r[4 * j] = a.x; r[4 * j + 1] = a.y; r[4 * j + 2] = a.z; r[4 * j + 3] = a.w;
  }
}

// per-(h,d) reduction helper: after xor 8/16/32, lanes 0..7 hold head sums
__device__ __forceinline__ float hred(float v) {
  v += __shfl_xor(v, 8, 64);
  v += __shfl_xor(v, 16, 64);
  v += __shfl_xor(v, 32, 64);
  return v;
}

// Pass A: sigmoid, write bf16 mirrors, accumulate qsum/ksum
template <bool MIR>
__global__ __launch_bounds__(256) void k_prep(const float* __restrict__ Q, const float* __restrict__ K,
                                              float* __restrict__ ws,
                                              unsigned short* __restrict__ sQ, unsigned short* __restrict__ sK) {
  const int tid = threadIdx.x;
  const int p = blockIdx.x * 256 + tid;
  float q[16], k[16];
  load_sig<false>(nullptr, Q, p, q);
  load_sig<false>(nullptr, K, p, k);
  if (MIR) {
    union U { unsigned short u[8]; uint4 v; };
    U a, b;
#pragma unroll
    for (int j = 0; j < 8; ++j) { a.u[j] = f2bf(q[j]); b.u[j] = f2bf(q[8 + j]); }
    uint4* dq = reinterpret_cast<uint4*>(sQ + (size_t)p * 16);
    dq[0] = a.v; dq[1] = b.v;
#pragma unroll
    for (int j = 0; j < 8; ++j) { a.u[j] = f2bf(k[j]); b.u[j] = f2bf(k[8 + j]); }
    uint4* dk = reinterpret_cast<uint4*>(sK + (size_t)p * 16);
    dk[0] = a.v; dk[1] = b.v;
  }
  __shared__ float sacc[256];  // [qk][h][d]
  sacc[tid] = 0.f;
  __syncthreads();
  const int lane = tid & 63;
#pragma unroll
  for (int d = 0; d < 16; ++d) {
    float v = hred(q[d]);
    if (lane < 8) atomicAdd(&sacc[lane * 16 + d], v);
    float w = hred(k[d]);
    if (lane < 8) atomicAdd(&sacc[128 + lane * 16 + d], w);
  }
  __syncthreads();
  const int n = (blockIdx.x * 32) >> 14;
  const int qk = tid >> 7, hd = tid & 127;
  atomicAdd(ws + (qk ? OFF_KSUM : OFF_QSUM) + n * 128 + hd, sacc[tid]);
}

// Pass B: qn += q*nr, kn += k*nc
template <bool MIR>
__global__ __launch_bounds__(256) void k_refine(const float* __restrict__ Q, const float* __restrict__ K,
                                                const unsigned short* __restrict__ sQ,
                                                const unsigned short* __restrict__ sK,
                                                float* __restrict__ ws) {
  const int tid = threadIdx.x;
  const int p = blockIdx.x * 256 + tid;
  const int n = (blockIdx.x * 32) >> 14;
  __shared__ float qsE[128], ksE[128], sacc[256];
  if (tid < 128) {
    qsE[tid] = ws[OFF_QSUM + n * 128 + tid] + EPS;
    ksE[tid] = ws[OFF_KSUM + n * 128 + tid] + EPS;
  }
  sacc[tid] = 0.f;
  __syncthreads();
  float q[16], k[16];
  load_sig<MIR>(sQ, Q, p, q);
  load_sig<MIR>(sK, K, p, k);
  const int h = tid & 7, lane = tid & 63;
  float dr = 0.f, dc = 0.f;
#pragma unroll
  for (int d = 0; d < 16; ++d) {
    dr += (q[d] + EPS) * ksE[h * 16 + d];
    dc += (k[d] + EPS) * qsE[h * 16 + d];
  }
  const float nr = __fdividef(1.f, dr), nc = __fdividef(1.f, dc);
#pragma unroll
  for (int d = 0; d < 16; ++d) {
    float v = hred(q[d] * nr);
    if (lane < 8) atomicAdd(&sacc[lane * 16 + d], v);
    float w = hred(k[d] * nc);
    if (lane < 8) atomicAdd(&sacc[128 + lane * 16 + d], w);
  }
  __syncthreads();
  const int qk = tid >> 7, hd = tid & 127;
  atomicAdd(ws + (qk ? OFF_KN : OFF_QN) + n * 128 + hd, sacc[tid]);
}

// Pass C: ssum[n,h] += exp(dot(k+eps, qn+eps))  (no max-sub; ncr is O(1))
template <bool MIR>
__global__ __launch_bounds__(256) void k_css(const float* __restrict__ K,
                                             const unsigned short* __restrict__ sK,
                                             float* __restrict__ ws) {
  const int tid = threadIdx.x;
  const int p = blockIdx.x * 256 + tid;
  const int n = (blockIdx.x * 32) >> 14;
  __shared__ float qnE[128];
  __shared__ float ss[8];
  if (tid < 128) qnE[tid] = ws[OFF_QN + n * 128 + tid] + EPS;
  if (tid < 8) ss[tid] = 0.f;
  __syncthreads();
  float k[16];
  load_sig<MIR>(sK, K, p, k);
  const int h = tid & 7, lane = tid & 63;
  float ncr = 0.f;
#pragma unroll
  for (int d = 0; d < 16; ++d) ncr += (k[d] + EPS) * qnE[h * 16 + d];
  float e = hred(__expf(ncr));
  if (lane < 8) atomicAdd(&ss[lane], e);
  __syncthreads();
  if (tid < 8) atomicAdd(ws + OFF_SSUM + n * 8 + tid, ss[tid]);
}

// Pass E: kv[n,h][d][e] += k[d]*w * v[e]
template <bool MIR>
__global__ __launch_bounds__(256) void k_kv(const float* __restrict__ K, const float* __restrict__ V,
                                            const unsigned short* __restrict__ sK,
                                            float* __restrict__ ws) {
  const int tid = threadIdx.x;
  const int rowBase = blockIdx.x * 64;
  const int n = rowBase >> 14;
  __shared__ float qnE[128];
  __shared__ float wsc[8];
  __shared__ __align__(16) float kw[256 * 16];
  __shared__ __align__(16) float vv[256 * 16];
  if (tid < 128) qnE[tid] = ws[OFF_QN + n * 128 + tid] + EPS;
  if (tid < 8) wsc[tid] = __fdividef((float)LL, ws[OFF_SSUM + n * 8 + tid]);
  __syncthreads();
  const int h = tid & 7, sub = tid >> 3;
  const int d0 = (sub & 7) * 2, e0 = (sub >> 3) * 4;
  float acc[2][4] = {{0.f, 0.f, 0.f, 0.f}, {0.f, 0.f, 0.f, 0.f}};
  for (int t = 0; t < 2; ++t) {
    const int p = (rowBase + t * 32) * 8 + tid;
    float k[16], v[16];
    load_sig<MIR>(sK, K, p, k);
    load_raw16(V, p, v);
    float ncr = 0.f;
#pragma unroll
    for (int d = 0; d < 16; ++d) ncr += (k[d] + EPS) * qnE[h * 16 + d];
    const float w = __expf(ncr) * wsc[h];
#pragma unroll
    for (int d = 0; d < 16; ++d) kw[tid * 16 + d] = k[d] * w;
#pragma unroll
    for (int e = 0; e < 16; ++e) vv[tid * 16 + e] = v[e];
    __syncthreads();
#pragma unroll 8
    for (int r = 0; r < 32; ++r) {
      const int idx = (r * 8 + h) * 16;
      const float2 kk = *reinterpret_cast<const float2*>(&kw[idx + d0]);
      const float4 vb = *reinterpret_cast<const float4*>(&vv[idx + e0]);
      acc[0][0] += kk.x * vb.x; acc[0][1] += kk.x * vb.y;
      acc[0][2] += kk.x * vb.z; acc[0][3] += kk.x * vb.w;
      acc[1][0] += kk.y * vb.x; acc[1][1] += kk.y * vb.y;
      acc[1][2] += kk.y * vb.z; acc[1][3] += kk.y * vb.w;
    }
    __syncthreads();
  }
  float* dst = ws + OFF_KV + (n * 8 + h) * 256;
#pragma unroll
  for (int i = 0; i < 2; ++i)
#pragma unroll
    for (int j = 0; j < 4; ++j) atomicAdd(dst + (d0 + i) * 16 + e0 + j, acc[i][j]);
}

// Pass F: x = q@kv * nr * nrr + v, LayerNorm, write out
template <bool MIR>
__global__ __launch_bounds__(256) void k_out(const float* __restrict__ Q, const float* __restrict__ V,
                                             const unsigned short* __restrict__ sQ,
                                             const float* __restrict__ gamma, const float* __restrict__ beta,
                                             const float* __restrict__ ws, float* __restrict__ out) {
  const int tid = threadIdx.x;
  const int p = blockIdx.x * 256 + tid;
  const int n = (blockIdx.x * 32) >> 14;
  __shared__ __align__(16) float kvs[8 * 260];  // pad 260 → bank-conflict-free by h
  __shared__ float ksE[128], knE[128], gm[16], bt[16];
  for (int i = tid; i < 2048; i += 256) {
    const int hh = i >> 8, de = i & 255;
    kvs[hh * 260 + de] = ws[OFF_KV + n * 2048 + i];
  }
  if (tid < 128) {
    ksE[tid] = ws[OFF_KSUM + n * 128 + tid] + EPS;
    knE[tid] = ws[OFF_KN + n * 128 + tid] + EPS;
  }
  if (tid < 16) gm[tid] = gamma[tid];
  else if (tid < 32) bt[tid - 16] = beta[tid - 16];
  __syncthreads();
  const int h = tid & 7;
  float q[16], v[16];
  load_sig<MIR>(sQ, Q, p, q);
  load_raw16(V, p, v);
  float dr = 0.f, drr = 0.f;
#pragma unroll
  for (int d = 0; d < 16; ++d) {
    const float qe = q[d] + EPS;
    dr += qe * ksE[h * 16 + d];
    drr += qe * knE[h * 16 + d];
  }
  const float sc = __fdividef(1.f, dr) * sigm(drr);
  float x[16];
#pragma unroll
  for (int e = 0; e < 16; ++e) x[e] = 0.f;
#pragma unroll
  for (int d = 0; d < 16; ++d) {
    const float qd = q[d];
    const float4* kr = reinterpret_cast<const float4*>(&kvs[h * 260 + d * 16]);
#pragma unroll
    for (int j = 0; j < 4; ++j) {
      float4 a = kr[j];
      x[4 * j] += qd * a.x; x[4 * j + 1] += qd * a.y;
      x[4 * j + 2] += qd * a.z; x[4 * j + 3] += qd * a.w;
    }
  }
#pragma unroll
  for (int e = 0; e < 16; ++e) x[e] = x[e] * sc + v[e];
  float mean = 0.f;
#pragma unroll
  for (int e = 0; e < 16; ++e) mean += x[e];
  mean *= (1.f / 16.f);
  float var = 0.f;
#pragma unroll
  for (int e = 0; e < 16; ++e) { const float t = x[e] - mean; var += t * t; }
  var *= (1.f / 16.f);
  const float inv = rsqrtf(var + LN_EPS);
  float y[16];
#pragma unroll
  for (int e = 0; e < 16; ++e) y[e] = (x[e] - mean) * inv * gm[e] + bt[e];
  float4* op = reinterpret_cast<float4*>(out + (size_t)p * 16);
  op[0] = make_float4(y[0], y[1], y[2], y[3]);
  op[1] = make_float4(y[4], y[5], y[6], y[7]);
  op[2] = make_float4(y[8], y[9], y[10], y[11]);
  op[3] = make_float4(y[12], y[13], y[14], y[15]);
}

extern "C" void kernel_launch(void* const* d_in, const int* in_sizes, int n_in,
                              void* d_out, int out_size, void* d_ws, size_t ws_size,
                              hipStream_t stream) {
  const float* Q = (const float*)d_in[0];
  const float* K = (const float*)d_in[1];
  const float* V = (const float*)d_in[2];
  const float* gamma = (const float*)d_in[3];
  const float* beta = (const float*)d_in[4];
  float* ws = (float*)d_ws;
  float* out = (float*)d_out;
  unsigned short* sQ = (unsigned short*)((char*)d_ws + MIR_Q_BYTE);
  unsigned short* sK = (unsigned short*)((char*)d_ws + MIR_K_BYTE);
  const bool mir = ws_size >= WS_NEED;

  hipMemsetAsync(d_ws, 0, (size_t)OFF_STATS_END * sizeof(float), stream);

  const dim3 blk(256);
  const int gPair = NPAIR / 256;  // 2048
  const int gKv = NROW / 64;      // 1024
  if (mir) {
    k_prep<true><<<gPair, blk, 0, stream>>>(Q, K, ws, sQ, sK);
    k_refine<true><<<gPair, blk, 0, stream>>>(Q, K, sQ, sK, ws);
    k_css<true><<<gPair, blk, 0, stream>>>(K, sK, ws);
    k_kv<true><<<gKv, blk, 0, stream>>>(K, V, sK, ws);
    k_out<true><<<gPair, blk, 0, stream>>>(Q, V, sQ, gamma, beta, ws, out);
  } else {
    k_prep<false><<<gPair, blk, 0, stream>>>(Q, K, ws, sQ, sK);
    k_refine<false><<<gPair, blk, 0, stream>>>(Q, K, sQ, sK, ws);
    k_css<false><<<gPair, blk, 0, stream>>>(K, sK, ws);
    k_kv<false><<<gKv, blk, 0, stream>>>(K, V, sK, ws);
    k_out<false><<<gPair, blk, 0, stream>>>(Q, V, sQ, gamma, beta, ws, out);
  }
}

// Round 3
// 282.523 us; speedup vs baseline: 1.7120x; 1.7120x over previous
//
#include <hip/hip_runtime.h>
#include <math.h>
#include <stdint.h>

constexpr int LL = 16384;
constexpr int NROW = 65536;          // N*L
constexpr int NPAIR = NROW * 8;      // 524288 (row,head) pairs
constexpr float EPS = 1e-6f;
constexpr float LN_EPS = 1e-5f;

// ws float offsets
constexpr int OFF_QSUM = 0;      // [4][128]
constexpr int OFF_KSUM = 512;
constexpr int OFF_QN   = 1024;
constexpr int OFF_KN   = 1536;
constexpr int OFF_SSUM = 2048;   // legacy path only
constexpr int OFF_KV   = 2112;   // [32][256]
constexpr int OFF_STATS_END = 10304;
constexpr int OFF_PA = 10304;                  // [2048][256] per-block stat partials
constexpr int OFF_PK = OFF_PA + 2048 * 256;    // [1024][2056] per-block KV partials (+8 ssum)
constexpr int FLOATS_PART_END = OFF_PK + 1024 * 2056;
constexpr size_t WS_PART = (size_t)FLOATS_PART_END * 4;
constexpr size_t MIR_Q_BYTE = WS_PART;
constexpr size_t MIR_ELEMS  = (size_t)NPAIR * 16;
constexpr size_t MIR_K_BYTE = MIR_Q_BYTE + MIR_ELEMS * 2;
constexpr size_t WS_FULL    = MIR_K_BYTE + MIR_ELEMS * 2;

__device__ __forceinline__ float sigm(float x) { return __fdividef(1.f, 1.f + __expf(-x)); }
__device__ __forceinline__ unsigned short f2bf(float f) {
  uint32_t x = __float_as_uint(f);
  return (unsigned short)((x + 0x7FFFu + ((x >> 16) & 1u)) >> 16);
}
__device__ __forceinline__ float bf2f(unsigned short u) {
  return __uint_as_float(((uint32_t)u) << 16);
}

template <bool MIR>
__device__ __forceinline__ void load_sig(const unsigned short* mir, const float* fp, int p, float* r) {
  if (MIR) {
    const uint4* p4 = reinterpret_cast<const uint4*>(mir + (size_t)p * 16);
    uint4 a = p4[0], b = p4[1];
    uint32_t w[8] = {a.x, a.y, a.z, a.w, b.x, b.y, b.z, b.w};
#pragma unroll
    for (int j = 0; j < 8; ++j) {
      r[2 * j]     = bf2f((unsigned short)(w[j] & 0xFFFFu));
      r[2 * j + 1] = bf2f((unsigned short)(w[j] >> 16));
    }
  } else {
    const float4* p4 = reinterpret_cast<const float4*>(fp + (size_t)p * 16);
#pragma unroll
    for (int j = 0; j < 4; ++j) {
      float4 a = p4[j];
      r[4 * j] = sigm(a.x); r[4 * j + 1] = sigm(a.y);
      r[4 * j + 2] = sigm(a.z); r[4 * j + 3] = sigm(a.w);
    }
  }
}
__device__ __forceinline__ void load_raw16(const float* fp, int p, float* r) {
  const float4* p4 = reinterpret_cast<const float4*>(fp + (size_t)p * 16);
#pragma unroll
  for (int j = 0; j < 4; ++j) {
    float4 a = p4[j];
    r[4 * j] = a.x; r[4 * j + 1] = a.y; r[4 * j + 2] = a.z; r[4 * j + 3] = a.w;
  }
}

// sums over the 8 lanes sharing (lane&7); every lane gets the group sum
__device__ __forceinline__ float hred(float v) {
  v += __shfl_xor(v, 8, 64);
  v += __shfl_xor(v, 16, 64);
  v += __shfl_xor(v, 32, 64);
  return v;
}

// ---------------- partials pipeline (paths A/B) ----------------

// prep: sigmoid, optional bf16 mirrors, per-block [qk][h][d] partial sums
template <bool MIR>
__global__ __launch_bounds__(256) void k_prep2(const float* __restrict__ Q, const float* __restrict__ K,
                                               float* __restrict__ ws,
                                               unsigned short* __restrict__ sQ, unsigned short* __restrict__ sK) {
  const int tid = threadIdx.x;
  const int p = blockIdx.x * 256 + tid;
  float q[16], k[16];
  load_sig<false>(nullptr, Q, p, q);
  load_sig<false>(nullptr, K, p, k);
  if (MIR) {
    union U { unsigned short u[8]; uint4 v; };
    U a, b;
#pragma unroll
    for (int j = 0; j < 8; ++j) { a.u[j] = f2bf(q[j]); b.u[j] = f2bf(q[8 + j]); }
    uint4* dq = reinterpret_cast<uint4*>(sQ + (size_t)p * 16);
    dq[0] = a.v; dq[1] = b.v;
#pragma unroll
    for (int j = 0; j < 8; ++j) { a.u[j] = f2bf(k[j]); b.u[j] = f2bf(k[8 + j]); }
    uint4* dk = reinterpret_cast<uint4*>(sK + (size_t)p * 16);
    dk[0] = a.v; dk[1] = b.v;
  }
  __shared__ float sacc[256];
  sacc[tid] = 0.f;
  __syncthreads();
  const int lane = tid & 63;
#pragma unroll
  for (int d = 0; d < 16; ++d) {
    float a = hred(q[d]);
    float b = hred(k[d]);
    if (lane < 8) {
      atomicAdd(&sacc[lane * 16 + d], a);
      atomicAdd(&sacc[128 + lane * 16 + d], b);
    }
  }
  __syncthreads();
  ws[OFF_PA + (size_t)blockIdx.x * 256 + tid] = sacc[tid];
}

// reduce 512 per-block partials per n → two [4][128] stat arrays
__global__ __launch_bounds__(1024) void k_red(const float* __restrict__ src,
                                              float* __restrict__ dA, float* __restrict__ dB) {
  const int n = blockIdx.x, tid = threadIdx.x;
  const int hd = tid & 255, c0 = tid >> 8;
  float acc = 0.f;
  const float* s = src + (size_t)n * 512 * 256;
  for (int c = c0; c < 512; c += 4) acc += s[(size_t)c * 256 + hd];
  __shared__ float sacc[1024];
  sacc[tid] = acc;
  __syncthreads();
  if (tid < 256) {
    float v = sacc[tid] + sacc[256 + tid] + sacc[512 + tid] + sacc[768 + tid];
    const int qk = tid >> 7, i = tid & 127;
    (qk ? dB : dA)[n * 128 + i] = v;
  }
}

// refine: per-block partial sums of q*nr and k*nc
template <bool MIR>
__global__ __launch_bounds__(256) void k_refine2(const float* __restrict__ Q, const float* __restrict__ K,
                                                 const unsigned short* __restrict__ sQ,
                                                 const unsigned short* __restrict__ sK,
                                                 float* __restrict__ ws) {
  const int tid = threadIdx.x;
  const int p = blockIdx.x * 256 + tid;
  const int n = blockIdx.x >> 9;
  __shared__ float qsE[128], ksE[128], sacc[256];
  if (tid < 128) {
    qsE[tid] = ws[OFF_QSUM + n * 128 + tid] + EPS;
    ksE[tid] = ws[OFF_KSUM + n * 128 + tid] + EPS;
  }
  sacc[tid] = 0.f;
  __syncthreads();
  float q[16], k[16];
  load_sig<MIR>(sQ, Q, p, q);
  load_sig<MIR>(sK, K, p, k);
  const int h = tid & 7, lane = tid & 63;
  float dr = 0.f, dc = 0.f;
#pragma unroll
  for (int d = 0; d < 16; ++d) {
    dr += (q[d] + EPS) * ksE[h * 16 + d];
    dc += (k[d] + EPS) * qsE[h * 16 + d];
  }
  const float nr = __fdividef(1.f, dr), nc = __fdividef(1.f, dc);
#pragma unroll
  for (int d = 0; d < 16; ++d) {
    float a = hred(q[d] * nr);
    float b = hred(k[d] * nc);
    if (lane < 8) {
      atomicAdd(&sacc[lane * 16 + d], a);
      atomicAdd(&sacc[128 + lane * 16 + d], b);
    }
  }
  __syncthreads();
  ws[OFF_PA + (size_t)blockIdx.x * 256 + tid] = sacc[tid];
}

// kv: per-block partial KV tiles (unscaled) + per-block exp-sum partials.
// LDS layout [ri][h*17 + d] → writes exactly 2-way (free); inner reads remapped
// so a wave touches only 2 heads (broadcast + ≤2-way).
template <bool MIR>
__global__ __launch_bounds__(256) void k_kv2(const float* __restrict__ K, const float* __restrict__ V,
                                             const unsigned short* __restrict__ sK,
                                             float* __restrict__ ws) {
  const int tid = threadIdx.x;
  const int blk = blockIdx.x;      // 1024 blocks × 64 rows
  const int n = blk >> 8;
  __shared__ float qnE[128];
  __shared__ float ssb[8];
  __shared__ float kwL[32 * 136];
  __shared__ float vL[32 * 136];
  if (tid < 128) qnE[tid] = ws[OFF_QN + n * 128 + tid] + EPS;
  if (tid < 8) ssb[tid] = 0.f;
  __syncthreads();
  const int h = tid & 7, ri = tid >> 3, lane = tid & 63;
  const int h2 = tid >> 5;
  const int d0 = ((tid >> 2) & 7) * 2;
  const int e0 = (tid & 3) * 4;
  float acc[2][4] = {{0.f, 0.f, 0.f, 0.f}, {0.f, 0.f, 0.f, 0.f}};
  for (int t = 0; t < 2; ++t) {
    const int p = (blk * 64 + t * 32) * 8 + tid;
    float k[16], v[16];
    load_sig<MIR>(sK, K, p, k);
    load_raw16(V, p, v);
    float ncr = 0.f;
#pragma unroll
    for (int d = 0; d < 16; ++d) ncr += (k[d] + EPS) * qnE[h * 16 + d];
    const float w = __expf(ncr);   // ncr is O(1): no max-subtraction needed
    float sw = hred(w);
    if (lane < 8) atomicAdd(&ssb[lane], sw);
    const int wb = ri * 136 + h * 17;
#pragma unroll
    for (int d = 0; d < 16; ++d) { kwL[wb + d] = k[d] * w; vL[wb + d] = v[d]; }
    __syncthreads();
    const int rb0 = h2 * 17;
#pragma unroll 4
    for (int r = 0; r < 32; ++r) {
      const int rb = r * 136 + rb0;
      const float ka = kwL[rb + d0], kb = kwL[rb + d0 + 1];
      const float v0 = vL[rb + e0], v1 = vL[rb + e0 + 1];
      const float v2 = vL[rb + e0 + 2], v3 = vL[rb + e0 + 3];
      acc[0][0] += ka * v0; acc[0][1] += ka * v1; acc[0][2] += ka * v2; acc[0][3] += ka * v3;
      acc[1][0] += kb * v0; acc[1][1] += kb * v1; acc[1][2] += kb * v2; acc[1][3] += kb * v3;
    }
    __syncthreads();
  }
  float* pk = ws + OFF_PK + (size_t)blk * 2056;
  *reinterpret_cast<float4*>(pk + h2 * 256 + d0 * 16 + e0) =
      make_float4(acc[0][0], acc[0][1], acc[0][2], acc[0][3]);
  *reinterpret_cast<float4*>(pk + h2 * 256 + (d0 + 1) * 16 + e0) =
      make_float4(acc[1][0], acc[1][1], acc[1][2], acc[1][3]);
  if (tid < 8) pk[2048 + tid] = ssb[tid];
}

// reduce KV partials, apply softmax scale L/ssum per (n,h)
__global__ __launch_bounds__(256) void k_kvred(float* __restrict__ ws) {
  const int nh = blockIdx.x, n = nh >> 3, h = nh & 7;
  const int tid = threadIdx.x;
  float acc = 0.f, ss = 0.f;
  const float* base = ws + OFF_PK + (size_t)n * 256 * 2056;
  for (int c = 0; c < 256; ++c) {
    const float* pk = base + (size_t)c * 2056;
    acc += pk[h * 256 + tid];
    ss += pk[2048 + h];
  }
  ws[OFF_KV + nh * 256 + tid] = acc * __fdividef((float)LL, ss);
}

// ---------------- legacy atomic path (tiny ws fallback) ----------------

__global__ __launch_bounds__(256) void k_prepL(const float* __restrict__ Q, const float* __restrict__ K,
                                               float* __restrict__ ws) {
  const int tid = threadIdx.x;
  const int p = blockIdx.x * 256 + tid;
  float q[16], k[16];
  load_sig<false>(nullptr, Q, p, q);
  load_sig<false>(nullptr, K, p, k);
  __shared__ float sacc[256];
  sacc[tid] = 0.f;
  __syncthreads();
  const int lane = tid & 63;
#pragma unroll
  for (int d = 0; d < 16; ++d) {
    float a = hred(q[d]);
    float b = hred(k[d]);
    if (lane < 8) { atomicAdd(&sacc[lane * 16 + d], a); atomicAdd(&sacc[128 + lane * 16 + d], b); }
  }
  __syncthreads();
  const int n = blockIdx.x >> 9;
  const int qk = tid >> 7, hd = tid & 127;
  atomicAdd(ws + (qk ? OFF_KSUM : OFF_QSUM) + n * 128 + hd, sacc[tid]);
}

__global__ __launch_bounds__(256) void k_refineL(const float* __restrict__ Q, const float* __restrict__ K,
                                                 float* __restrict__ ws) {
  const int tid = threadIdx.x;
  const int p = blockIdx.x * 256 + tid;
  const int n = blockIdx.x >> 9;
  __shared__ float qsE[128], ksE[128], sacc[256];
  if (tid < 128) {
    qsE[tid] = ws[OFF_QSUM + n * 128 + tid] + EPS;
    ksE[tid] = ws[OFF_KSUM + n * 128 + tid] + EPS;
  }
  sacc[tid] = 0.f;
  __syncthreads();
  float q[16], k[16];
  load_sig<false>(nullptr, Q, p, q);
  load_sig<false>(nullptr, K, p, k);
  const int h = tid & 7, lane = tid & 63;
  float dr = 0.f, dc = 0.f;
#pragma unroll
  for (int d = 0; d < 16; ++d) {
    dr += (q[d] + EPS) * ksE[h * 16 + d];
    dc += (k[d] + EPS) * qsE[h * 16 + d];
  }
  const float nr = __fdividef(1.f, dr), nc = __fdividef(1.f, dc);
#pragma unroll
  for (int d = 0; d < 16; ++d) {
    float a = hred(q[d] * nr);
    float b = hred(k[d] * nc);
    if (lane < 8) { atomicAdd(&sacc[lane * 16 + d], a); atomicAdd(&sacc[128 + lane * 16 + d], b); }
  }
  __syncthreads();
  const int qk = tid >> 7, hd = tid & 127;
  atomicAdd(ws + (qk ? OFF_KN : OFF_QN) + n * 128 + hd, sacc[tid]);
}

__global__ __launch_bounds__(256) void k_cssL(const float* __restrict__ K, float* __restrict__ ws) {
  const int tid = threadIdx.x;
  const int p = blockIdx.x * 256 + tid;
  const int n = blockIdx.x >> 9;
  __shared__ float qnE[128];
  __shared__ float ss[8];
  if (tid < 128) qnE[tid] = ws[OFF_QN + n * 128 + tid] + EPS;
  if (tid < 8) ss[tid] = 0.f;
  __syncthreads();
  float k[16];
  load_sig<false>(nullptr, K, p, k);
  const int h = tid & 7, lane = tid & 63;
  float ncr = 0.f;
#pragma unroll
  for (int d = 0; d < 16; ++d) ncr += (k[d] + EPS) * qnE[h * 16 + d];
  float e = hred(__expf(ncr));
  if (lane < 8) atomicAdd(&ss[lane], e);
  __syncthreads();
  if (tid < 8) atomicAdd(ws + OFF_SSUM + n * 8 + tid, ss[tid]);
}

__global__ __launch_bounds__(256) void k_kvL(const float* __restrict__ K, const float* __restrict__ V,
                                             float* __restrict__ ws) {
  const int tid = threadIdx.x;
  const int blk = blockIdx.x;
  const int n = blk >> 8;
  __shared__ float qnE[128];
  __shared__ float wsc[8];
  __shared__ float kwL[32 * 136];
  __shared__ float vL[32 * 136];
  __shared__ float ssb[8];
  if (tid < 128) qnE[tid] = ws[OFF_QN + n * 128 + tid] + EPS;
  if (tid < 8) { wsc[tid] = __fdividef((float)LL, ws[OFF_SSUM + n * 8 + tid]); ssb[tid] = 0.f; }
  __syncthreads();
  const int h = tid & 7, ri = tid >> 3;
  const int h2 = tid >> 5;
  const int d0 = ((tid >> 2) & 7) * 2;
  const int e0 = (tid & 3) * 4;
  float acc[2][4] = {{0.f, 0.f, 0.f, 0.f}, {0.f, 0.f, 0.f, 0.f}};
  for (int t = 0; t < 2; ++t) {
    const int p = (blk * 64 + t * 32) * 8 + tid;
    float k[16], v[16];
    load_sig<false>(nullptr, K, p, k);
    load_raw16(V, p, v);
    float ncr = 0.f;
#pragma unroll
    for (int d = 0; d < 16; ++d) ncr += (k[d] + EPS) * qnE[h * 16 + d];
    const float w = __expf(ncr) * wsc[h];
    const int wb = ri * 136 + h * 17;
#pragma unroll
    for (int d = 0; d < 16; ++d) { kwL[wb + d] = k[d] * w; vL[wb + d] = v[d]; }
    __syncthreads();
    const int rb0 = h2 * 17;
#pragma unroll 4
    for (int r = 0; r < 32; ++r) {
      const int rb = r * 136 + rb0;
      const float ka = kwL[rb + d0], kb = kwL[rb + d0 + 1];
      const float v0 = vL[rb + e0], v1 = vL[rb + e0 + 1];
      const float v2 = vL[rb + e0 + 2], v3 = vL[rb + e0 + 3];
      acc[0][0] += ka * v0; acc[0][1] += ka * v1; acc[0][2] += ka * v2; acc[0][3] += ka * v3;
      acc[1][0] += kb * v0; acc[1][1] += kb * v1; acc[1][2] += kb * v2; acc[1][3] += kb * v3;
    }
    __syncthreads();
  }
  float* dst = ws + OFF_KV + (n * 8 + h2) * 256;
#pragma unroll
  for (int i = 0; i < 2; ++i)
#pragma unroll
    for (int j = 0; j < 4; ++j) atomicAdd(dst + (d0 + i) * 16 + e0 + j, acc[i][j]);
}

// ---------------- epilogue (shared) ----------------

template <bool MIR>
__global__ __launch_bounds__(256) void k_out(const float* __restrict__ Q, const float* __restrict__ V,
                                             const unsigned short* __restrict__ sQ,
                                             const float* __restrict__ gamma, const float* __restrict__ beta,
                                             const float* __restrict__ ws, float* __restrict__ out) {
  const int tid = threadIdx.x;
  const int p = blockIdx.x * 256 + tid;
  const int n = blockIdx.x >> 9;
  __shared__ __align__(16) float kvs[8 * 260];
  __shared__ float ksE[128], knE[128], gm[16], bt[16];
  for (int i = tid; i < 2048; i += 256) {
    const int hh = i >> 8, de = i & 255;
    kvs[hh * 260 + de] = ws[OFF_KV + n * 2048 + i];
  }
  if (tid < 128) {
    ksE[tid] = ws[OFF_KSUM + n * 128 + tid] + EPS;
    knE[tid] = ws[OFF_KN + n * 128 + tid] + EPS;
  }
  if (tid < 16) gm[tid] = gamma[tid];
  else if (tid < 32) bt[tid - 16] = beta[tid - 16];
  __syncthreads();
  const int h = tid & 7;
  float q[16], v[16];
  load_sig<MIR>(sQ, Q, p, q);
  load_raw16(V, p, v);
  float dr = 0.f, drr = 0.f;
#pragma unroll
  for (int d = 0; d < 16; ++d) {
    const float qe = q[d] + EPS;
    dr += qe * ksE[h * 16 + d];
    drr += qe * knE[h * 16 + d];
  }
  const float sc = __fdividef(1.f, dr) * sigm(drr);
  float x[16];
#pragma unroll
  for (int e = 0; e < 16; ++e) x[e] = 0.f;
#pragma unroll
  for (int d = 0; d < 16; ++d) {
    const float qd = q[d];
    const float4* kr = reinterpret_cast<const float4*>(&kvs[h * 260 + d * 16]);
#pragma unroll
    for (int j = 0; j < 4; ++j) {
      float4 a = kr[j];
      x[4 * j] += qd * a.x; x[4 * j + 1] += qd * a.y;
      x[4 * j + 2] += qd * a.z; x[4 * j + 3] += qd * a.w;
    }
  }
#pragma unroll
  for (int e = 0; e < 16; ++e) x[e] = x[e] * sc + v[e];
  float mean = 0.f;
#pragma unroll
  for (int e = 0; e < 16; ++e) mean += x[e];
  mean *= (1.f / 16.f);
  float var = 0.f;
#pragma unroll
  for (int e = 0; e < 16; ++e) { const float t = x[e] - mean; var += t * t; }
  var *= (1.f / 16.f);
  const float inv = rsqrtf(var + LN_EPS);
  float y[16];
#pragma unroll
  for (int e = 0; e < 16; ++e) y[e] = (x[e] - mean) * inv * gm[e] + bt[e];
  float4* op = reinterpret_cast<float4*>(out + (size_t)p * 16);
  op[0] = make_float4(y[0], y[1], y[2], y[3]);
  op[1] = make_float4(y[4], y[5], y[6], y[7]);
  op[2] = make_float4(y[8], y[9], y[10], y[11]);
  op[3] = make_float4(y[12], y[13], y[14], y[15]);
}

extern "C" void kernel_launch(void* const* d_in, const int* in_sizes, int n_in,
                              void* d_out, int out_size, void* d_ws, size_t ws_size,
                              hipStream_t stream) {
  const float* Q = (const float*)d_in[0];
  const float* K = (const float*)d_in[1];
  const float* V = (const float*)d_in[2];
  const float* gamma = (const float*)d_in[3];
  const float* beta = (const float*)d_in[4];
  float* ws = (float*)d_ws;
  float* out = (float*)d_out;
  unsigned short* sQ = (unsigned short*)((char*)d_ws + MIR_Q_BYTE);
  unsigned short* sK = (unsigned short*)((char*)d_ws + MIR_K_BYTE);

  const dim3 blk(256);
  const int gPair = NPAIR / 256;  // 2048
  const int gKv = NROW / 64;      // 1024

  if (ws_size >= WS_FULL) {
    k_prep2<true><<<gPair, blk, 0, stream>>>(Q, K, ws, sQ, sK);
    k_red<<<4, 1024, 0, stream>>>(ws + OFF_PA, ws + OFF_QSUM, ws + OFF_KSUM);
    k_refine2<true><<<gPair, blk, 0, stream>>>(Q, K, sQ, sK, ws);
    k_red<<<4, 1024, 0, stream>>>(ws + OFF_PA, ws + OFF_QN, ws + OFF_KN);
    k_kv2<true><<<gKv, blk, 0, stream>>>(K, V, sK, ws);
    k_kvred<<<32, blk, 0, stream>>>(ws);
    k_out<true><<<gPair, blk, 0, stream>>>(Q, V, sQ, gamma, beta, ws, out);
  } else if (ws_size >= WS_PART) {
    k_prep2<false><<<gPair, blk, 0, stream>>>(Q, K, ws, sQ, sK);
    k_red<<<4, 1024, 0, stream>>>(ws + OFF_PA, ws + OFF_QSUM, ws + OFF_KSUM);
    k_refine2<false><<<gPair, blk, 0, stream>>>(Q, K, sQ, sK, ws);
    k_red<<<4, 1024, 0, stream>>>(ws + OFF_PA, ws + OFF_QN, ws + OFF_KN);
    k_kv2<false><<<gKv, blk, 0, stream>>>(K, V, sK, ws);
    k_kvred<<<32, blk, 0, stream>>>(ws);
    k_out<false><<<gPair, blk, 0, stream>>>(Q, V, sQ, gamma, beta, ws, out);
  } else {
    hipMemsetAsync(d_ws, 0, (size_t)OFF_STATS_END * sizeof(float), stream);
    k_prepL<<<gPair, blk, 0, stream>>>(Q, K, ws);
    k_refineL<<<gPair, blk, 0, stream>>>(Q, K, ws);
    k_cssL<<<gPair, blk, 0, stream>>>(K, ws);
    k_kvL<<<gKv, blk, 0, stream>>>(K, V, ws);
    k_out<false><<<gPair, blk, 0, stream>>>(Q, V, sQ, gamma, beta, ws, out);
  }
}